// Round 1
// baseline (10792.112 us; speedup 1.0000x reference)
//
#include <hip/hip_runtime.h>
#include <math.h>

#define B 8
#define M 256
#define D 65536

static constexpr float ALPHA = 0.5f;
static constexpr int N_ITERS = 50;
static constexpr int N_POWER = 10;

// ---------------------------------------------------------------------------
// K1: y[b,m] = dot(A[b,m,:], x[b,:]);  u0[b,m] = rowsum(A[b,m,:]) / sqrt(D)
// grid: B*M = 2048 blocks x 256 threads
// ---------------------------------------------------------------------------
__global__ __launch_bounds__(256) void k_y_u0(const float* __restrict__ A,
                                              const float* __restrict__ x,
                                              float* __restrict__ y,
                                              float* __restrict__ u) {
    int bm = blockIdx.x;
    int b = bm >> 8;
    const float4* arow = (const float4*)(A + (size_t)bm * D);
    const float4* xrow = (const float4*)(x + (size_t)b * D);
    float sy = 0.f, ss = 0.f;
#pragma unroll 8
    for (int i = threadIdx.x; i < D / 4; i += 256) {
        float4 a = arow[i];
        float4 xv = xrow[i];
        sy += a.x * xv.x + a.y * xv.y + a.z * xv.z + a.w * xv.w;
        ss += a.x + a.y + a.z + a.w;
    }
    __shared__ float sdata[8];
    for (int off = 32; off > 0; off >>= 1) {
        sy += __shfl_down(sy, off, 64);
        ss += __shfl_down(ss, off, 64);
    }
    int lane = threadIdx.x & 63, wid = threadIdx.x >> 6;
    if (lane == 0) { sdata[wid] = sy; sdata[4 + wid] = ss; }
    __syncthreads();
    if (threadIdx.x == 0) {
        y[bm] = sdata[0] + sdata[1] + sdata[2] + sdata[3];
        u[bm] = (sdata[4] + sdata[5] + sdata[6] + sdata[7]) * 0.00390625f; // 1/sqrt(65536)
    }
}

// ---------------------------------------------------------------------------
// K2: Gram G[b] = A[b] * A[b]^T   (256x256), tiled 64x64, K-split into 8
// chunks of 8192 with atomic accumulation. Only tile pairs i<=j computed;
// off-diagonal pairs also write the transpose.
// grid: 8 batches * 10 pairs * 8 chunks = 640 blocks x 256 threads
// ---------------------------------------------------------------------------
__global__ __launch_bounds__(256) void k_gram(const float* __restrict__ A,
                                              float* __restrict__ G) {
    const int PI[10] = {0, 0, 0, 0, 1, 1, 1, 2, 2, 3};
    const int PJ[10] = {0, 1, 2, 3, 1, 2, 3, 2, 3, 3};
    int idx = blockIdx.x;
    int ch = idx & 7; idx >>= 3;
    int p = idx % 10;
    int b = idx / 10;
    int ti = PI[p] * 64, tj = PJ[p] * 64;
    int k0 = ch * 8192;

    __shared__ __align__(16) float As[16][68];
    __shared__ __align__(16) float Bs[16][68];

    int t = threadIdx.x;
    int lrow = t >> 2;           // 0..63
    int lk = (t & 3) << 2;       // 0,4,8,12
    int r0 = (t >> 4) << 2;      // 0..60
    int c0 = (t & 15) << 2;      // 0..60

    const float* Ab = A + (size_t)b * M * D;
    float acc[4][4] = {};

    for (int ks = 0; ks < 8192; ks += 16) {
        float4 av = *(const float4*)(Ab + (size_t)(ti + lrow) * D + k0 + ks + lk);
        float4 bv = *(const float4*)(Ab + (size_t)(tj + lrow) * D + k0 + ks + lk);
        __syncthreads();  // previous stage compute done before overwrite
        As[lk + 0][lrow] = av.x; As[lk + 1][lrow] = av.y;
        As[lk + 2][lrow] = av.z; As[lk + 3][lrow] = av.w;
        Bs[lk + 0][lrow] = bv.x; Bs[lk + 1][lrow] = bv.y;
        Bs[lk + 2][lrow] = bv.z; Bs[lk + 3][lrow] = bv.w;
        __syncthreads();
#pragma unroll
        for (int k = 0; k < 16; ++k) {
            float4 a = *(const float4*)&As[k][r0];
            float4 c = *(const float4*)&Bs[k][c0];
            float avv[4] = {a.x, a.y, a.z, a.w};
            float cvv[4] = {c.x, c.y, c.z, c.w};
#pragma unroll
            for (int i = 0; i < 4; ++i)
#pragma unroll
                for (int j = 0; j < 4; ++j)
                    acc[i][j] += avv[i] * cvv[j];
        }
    }
    float* Gb = G + (size_t)b * M * M;
    bool offdiag = (ti != tj);
#pragma unroll
    for (int i = 0; i < 4; ++i)
#pragma unroll
        for (int j = 0; j < 4; ++j) {
            atomicAdd(&Gb[(size_t)(ti + r0 + i) * M + (tj + c0 + j)], acc[i][j]);
            if (offdiag)
                atomicAdd(&Gb[(size_t)(tj + c0 + j) * M + (ti + r0 + i)], acc[i][j]);
        }
}

// ---------------------------------------------------------------------------
// K3: power iteration in M-space. u_{k+1} = G u_k / (||A^T u_k|| + 1e-12),
// ||A^T u_k|| = sqrt(u^T G u).  After N_POWER steps: L = ||u||^2 / M.
// Stores per batch: Lp[4b+0]=L, [4b+1]=1/(M*L), [4b+2]=ALPHA/L.
// grid: 8 blocks x 256 threads
// ---------------------------------------------------------------------------
__global__ __launch_bounds__(256) void k_power(const float* __restrict__ G,
                                               const float* __restrict__ u0,
                                               float* __restrict__ Lp) {
    int b = blockIdx.x;
    int m = threadIdx.x;
    __shared__ float su[M];
    __shared__ float red[4];
    su[m] = u0[b * M + m];
    __syncthreads();
    const float* Gb = G + (size_t)b * M * M;
    for (int it = 0; it < N_POWER; ++it) {
        float gm = 0.f;
        const float4* grow = (const float4*)(Gb + (size_t)m * M);
#pragma unroll 8
        for (int k = 0; k < M / 4; ++k) {
            float4 g = grow[k];
            gm += g.x * su[4 * k] + g.y * su[4 * k + 1] + g.z * su[4 * k + 2] +
                  g.w * su[4 * k + 3];
        }
        float part = su[m] * gm;
        for (int off = 32; off > 0; off >>= 1) part += __shfl_down(part, off, 64);
        if ((m & 63) == 0) red[m >> 6] = part;
        __syncthreads();
        float n = sqrtf(red[0] + red[1] + red[2] + red[3]);
        float inv = 1.f / (n + 1e-12f);
        su[m] = gm * inv;
        __syncthreads();
    }
    float part = su[m] * su[m];
    for (int off = 32; off > 0; off >>= 1) part += __shfl_down(part, off, 64);
    if ((m & 63) == 0) red[m >> 6] = part;
    __syncthreads();
    if (m == 0) {
        float L = (red[0] + red[1] + red[2] + red[3]) * (1.0f / 256.0f);
        Lp[b * 4 + 0] = L;
        Lp[b * 4 + 1] = 1.0f / (256.0f * L);
        Lp[b * 4 + 2] = ALPHA / L;
    }
}

// ---------------------------------------------------------------------------
// K4a: c[b,m] = (dot(A[b,m,:], z[b,:]) - y[b,m]) * (1/(M*L_b))
// grid: 2048 blocks x 256 threads
// ---------------------------------------------------------------------------
__global__ __launch_bounds__(256) void k_resid(const float* __restrict__ A,
                                               const float* __restrict__ z,
                                               const float* __restrict__ y,
                                               const float* __restrict__ Lp,
                                               float* __restrict__ c) {
    int bm = blockIdx.x;
    int b = bm >> 8;
    const float4* arow = (const float4*)(A + (size_t)bm * D);
    const float4* zrow = (const float4*)(z + (size_t)b * D);
    float s = 0.f;
#pragma unroll 8
    for (int i = threadIdx.x; i < D / 4; i += 256) {
        float4 a = arow[i];
        float4 zv = zrow[i];
        s += a.x * zv.x + a.y * zv.y + a.z * zv.z + a.w * zv.w;
    }
    __shared__ float red[4];
    for (int off = 32; off > 0; off >>= 1) s += __shfl_down(s, off, 64);
    if ((threadIdx.x & 63) == 0) red[threadIdx.x >> 6] = s;
    __syncthreads();
    if (threadIdx.x == 0) {
        float sv = red[0] + red[1] + red[2] + red[3];
        c[bm] = (sv - y[bm]) * Lp[b * 4 + 1];
    }
}

// ---------------------------------------------------------------------------
// K4b: candidate = z - A^T c ; w_new = soft(candidate, ALPHA/L);
//      z_new = w_new + beta*(w_new - w_old); store w (d_out) and z.
// Each block: batch b, 1024-wide d-tile, thread owns 4 d's (float4).
// grid: 8 * 64 = 512 blocks x 256 threads
// ---------------------------------------------------------------------------
__global__ __launch_bounds__(256) void k_update(const float* __restrict__ A,
                                                const float* __restrict__ cc,
                                                const float* __restrict__ Lp,
                                                float* __restrict__ z,
                                                float* __restrict__ w,
                                                float beta) {
    int blk = blockIdx.x;
    int b = blk >> 6;
    int dt = (blk & 63) << 10;
    __shared__ float sc[M];
    sc[threadIdx.x] = cc[b * M + threadIdx.x];
    __syncthreads();

    const float* Ap = A + (size_t)b * M * D + dt + (threadIdx.x << 2);
    float4 acc = {0.f, 0.f, 0.f, 0.f};
#pragma unroll 4
    for (int m = 0; m < M; ++m) {
        float4 a = *(const float4*)Ap;
        Ap += D;
        float cm = sc[m];
        acc.x += a.x * cm;
        acc.y += a.y * cm;
        acc.z += a.z * cm;
        acc.w += a.w * cm;
    }
    size_t zi = (size_t)b * D + dt + (threadIdx.x << 2);
    float4 zv = *(const float4*)(z + zi);
    float4 wv = *(const float4*)(w + zi);
    float thr = Lp[b * 4 + 2];

    float4 wn, zn;
    {
        float cand = zv.x - acc.x; float a1 = fabsf(cand) - thr;
        wn.x = a1 > 0.f ? copysignf(a1, cand) : 0.f;
        zn.x = wn.x + beta * (wn.x - wv.x);
    }
    {
        float cand = zv.y - acc.y; float a1 = fabsf(cand) - thr;
        wn.y = a1 > 0.f ? copysignf(a1, cand) : 0.f;
        zn.y = wn.y + beta * (wn.y - wv.y);
    }
    {
        float cand = zv.z - acc.z; float a1 = fabsf(cand) - thr;
        wn.z = a1 > 0.f ? copysignf(a1, cand) : 0.f;
        zn.z = wn.z + beta * (wn.z - wv.z);
    }
    {
        float cand = zv.w - acc.w; float a1 = fabsf(cand) - thr;
        wn.w = a1 > 0.f ? copysignf(a1, cand) : 0.f;
        zn.w = wn.w + beta * (wn.w - wv.w);
    }
    *(float4*)(w + zi) = wn;
    *(float4*)(z + zi) = zn;
}

// ---------------------------------------------------------------------------
extern "C" void kernel_launch(void* const* d_in, const int* in_sizes, int n_in,
                              void* d_out, int out_size, void* d_ws, size_t ws_size,
                              hipStream_t stream) {
    (void)in_sizes; (void)n_in; (void)out_size; (void)ws_size;
    const float* x = (const float*)d_in[0];        // [B, D]
    const float* A = (const float*)d_in[1];        // [B, M, D]
    float* w = (float*)d_out;                      // [B, D]
    float* ws = (float*)d_ws;

    float* y  = ws;                 // 2048
    float* u  = ws + 2048;          // 2048
    float* Lp = ws + 4096;          // 32
    float* c  = ws + 4128;          // 2048
    float* z  = ws + 8192;          // 524288 (16B aligned)
    float* G  = ws + 8192 + 524288; // 524288

    hipMemsetAsync(G, 0, (size_t)B * M * M * sizeof(float), stream);
    hipMemsetAsync(z, 0, (size_t)B * D * sizeof(float), stream);
    hipMemsetAsync(w, 0, (size_t)B * D * sizeof(float), stream);

    k_y_u0<<<B * M, 256, 0, stream>>>(A, x, y, u);
    k_gram<<<B * 10 * 8, 256, 0, stream>>>(A, G);
    k_power<<<B, 256, 0, stream>>>(G, u, Lp);

    double t = 1.0;
    for (int k = 0; k < N_ITERS; ++k) {
        double tn = 0.5 * (1.0 + sqrt(1.0 + 4.0 * t * t));
        float beta = (float)((t - 1.0) / tn);
        k_resid<<<B * M, 256, 0, stream>>>(A, z, y, Lp, c);
        k_update<<<B * 64, 256, 0, stream>>>(A, c, Lp, z, w, beta);
        t = tn;
    }
}

// Round 2
// 6392.838 us; speedup vs baseline: 1.6882x; 1.6882x over previous
//
#include <hip/hip_runtime.h>
#include <hip/hip_fp16.h>
#include <math.h>

#define B 8
#define M 256
#define D 65536

static constexpr float ALPHA = 0.5f;
static constexpr int N_ITERS = 50;
static constexpr int N_POWER = 10;

// ---------------------------------------------------------------------------
// K0: convert A fp32 -> fp16 (consistent quantization; all later math uses Ah)
// ---------------------------------------------------------------------------
__global__ __launch_bounds__(256) void k_conv(const float* __restrict__ A,
                                              __half* __restrict__ Ah) {
    const size_t n8 = (size_t)B * M * D / 8;  // 16,777,216 groups of 8
    size_t stride = (size_t)gridDim.x * 256;
    for (size_t i = (size_t)blockIdx.x * 256 + threadIdx.x; i < n8; i += stride) {
        float4 f0 = ((const float4*)A)[2 * i];
        float4 f1 = ((const float4*)A)[2 * i + 1];
        union { uint4 u; __half2 h[4]; } o;
        o.h[0] = __floats2half2_rn(f0.x, f0.y);
        o.h[1] = __floats2half2_rn(f0.z, f0.w);
        o.h[2] = __floats2half2_rn(f1.x, f1.y);
        o.h[3] = __floats2half2_rn(f1.z, f1.w);
        ((uint4*)Ah)[i] = o.u;
    }
}

// ---------------------------------------------------------------------------
// K1: y[b,m] = dot(Ah[b,m,:], x[b,:]);  u0[b,m] = rowsum(Ah[b,m,:]) / sqrt(D)
// grid: B*M = 2048 blocks x 256 threads
// ---------------------------------------------------------------------------
__global__ __launch_bounds__(256) void k_y_u0(const __half* __restrict__ Ah,
                                              const float* __restrict__ x,
                                              float* __restrict__ y,
                                              float* __restrict__ u) {
    int bm = blockIdx.x;
    int b = bm >> 8;
    const uint4* arow = (const uint4*)(Ah + (size_t)bm * D);
    const float4* xrow = (const float4*)(x + (size_t)b * D);
    float sy = 0.f, ss = 0.f;
#pragma unroll 4
    for (int i = threadIdx.x; i < D / 8; i += 256) {
        uint4 a = arow[i];
        const __half2* hp = (const __half2*)&a;
        float4 x0 = xrow[2 * i], x1 = xrow[2 * i + 1];
        float2 f0 = __half22float2(hp[0]);
        float2 f1 = __half22float2(hp[1]);
        float2 f2 = __half22float2(hp[2]);
        float2 f3 = __half22float2(hp[3]);
        sy += f0.x * x0.x + f0.y * x0.y + f1.x * x0.z + f1.y * x0.w +
              f2.x * x1.x + f2.y * x1.y + f3.x * x1.z + f3.y * x1.w;
        ss += f0.x + f0.y + f1.x + f1.y + f2.x + f2.y + f3.x + f3.y;
    }
    __shared__ float sdata[8];
    for (int off = 32; off > 0; off >>= 1) {
        sy += __shfl_down(sy, off, 64);
        ss += __shfl_down(ss, off, 64);
    }
    int lane = threadIdx.x & 63, wid = threadIdx.x >> 6;
    if (lane == 0) { sdata[wid] = sy; sdata[4 + wid] = ss; }
    __syncthreads();
    if (threadIdx.x == 0) {
        y[bm] = sdata[0] + sdata[1] + sdata[2] + sdata[3];
        u[bm] = (sdata[4] + sdata[5] + sdata[6] + sdata[7]) * 0.00390625f;
    }
}

// ---------------------------------------------------------------------------
// K2: Gram G[b] = Ah[b] * Ah[b]^T (256x256), 64x64 tiles, 16 K-chunks of 4096
// grid: 8 * 10 * 16 = 1280 blocks x 256 threads  (5 blocks/CU for occupancy)
// ---------------------------------------------------------------------------
__global__ __launch_bounds__(256) void k_gram(const __half* __restrict__ Ah,
                                              float* __restrict__ G) {
    const int PI[10] = {0, 0, 0, 0, 1, 1, 1, 2, 2, 3};
    const int PJ[10] = {0, 1, 2, 3, 1, 2, 3, 2, 3, 3};
    int idx = blockIdx.x;
    int ch = idx & 15; idx >>= 4;
    int p = idx % 10;
    int b = idx / 10;
    int ti = PI[p] * 64, tj = PJ[p] * 64;
    int k0 = ch * 4096;

    __shared__ __align__(16) float As[16][68];
    __shared__ __align__(16) float Bs[16][68];

    int t = threadIdx.x;
    int lrow = t >> 2;           // 0..63
    int lk = (t & 3) << 2;       // 0,4,8,12
    int r0 = (t >> 4) << 2;      // 0..60
    int c0 = (t & 15) << 2;      // 0..60

    const __half* Ab = Ah + (size_t)b * M * D;
    float acc[4][4] = {};

    for (int ks = 0; ks < 4096; ks += 16) {
        uint2 au = *(const uint2*)(Ab + (size_t)(ti + lrow) * D + k0 + ks + lk);
        uint2 bu = *(const uint2*)(Ab + (size_t)(tj + lrow) * D + k0 + ks + lk);
        const __half2* ah = (const __half2*)&au;
        const __half2* bh = (const __half2*)&bu;
        float2 a0 = __half22float2(ah[0]), a1 = __half22float2(ah[1]);
        float2 b0 = __half22float2(bh[0]), b1 = __half22float2(bh[1]);
        __syncthreads();  // previous stage compute done before overwrite
        As[lk + 0][lrow] = a0.x; As[lk + 1][lrow] = a0.y;
        As[lk + 2][lrow] = a1.x; As[lk + 3][lrow] = a1.y;
        Bs[lk + 0][lrow] = b0.x; Bs[lk + 1][lrow] = b0.y;
        Bs[lk + 2][lrow] = b1.x; Bs[lk + 3][lrow] = b1.y;
        __syncthreads();
#pragma unroll
        for (int k = 0; k < 16; ++k) {
            float4 a = *(const float4*)&As[k][r0];
            float4 c = *(const float4*)&Bs[k][c0];
            float avv[4] = {a.x, a.y, a.z, a.w};
            float cvv[4] = {c.x, c.y, c.z, c.w};
#pragma unroll
            for (int i = 0; i < 4; ++i)
#pragma unroll
                for (int j = 0; j < 4; ++j)
                    acc[i][j] += avv[i] * cvv[j];
        }
    }
    float* Gb = G + (size_t)b * M * M;
    bool offdiag = (ti != tj);
#pragma unroll
    for (int i = 0; i < 4; ++i)
#pragma unroll
        for (int j = 0; j < 4; ++j) {
            atomicAdd(&Gb[(size_t)(ti + r0 + i) * M + (tj + c0 + j)], acc[i][j]);
            if (offdiag)
                atomicAdd(&Gb[(size_t)(tj + c0 + j) * M + (ti + r0 + i)], acc[i][j]);
        }
}

// ---------------------------------------------------------------------------
// K3: power iteration in M-space (unchanged, G is tiny fp32).
// ---------------------------------------------------------------------------
__global__ __launch_bounds__(256) void k_power(const float* __restrict__ G,
                                               const float* __restrict__ u0,
                                               float* __restrict__ Lp) {
    int b = blockIdx.x;
    int m = threadIdx.x;
    __shared__ float su[M];
    __shared__ float red[4];
    su[m] = u0[b * M + m];
    __syncthreads();
    const float* Gb = G + (size_t)b * M * M;
    for (int it = 0; it < N_POWER; ++it) {
        float gm = 0.f;
        const float4* grow = (const float4*)(Gb + (size_t)m * M);
#pragma unroll 8
        for (int k = 0; k < M / 4; ++k) {
            float4 g = grow[k];
            gm += g.x * su[4 * k] + g.y * su[4 * k + 1] + g.z * su[4 * k + 2] +
                  g.w * su[4 * k + 3];
        }
        float part = su[m] * gm;
        for (int off = 32; off > 0; off >>= 1) part += __shfl_down(part, off, 64);
        if ((m & 63) == 0) red[m >> 6] = part;
        __syncthreads();
        float n = sqrtf(red[0] + red[1] + red[2] + red[3]);
        float inv = 1.f / (n + 1e-12f);
        su[m] = gm * inv;
        __syncthreads();
    }
    float part = su[m] * su[m];
    for (int off = 32; off > 0; off >>= 1) part += __shfl_down(part, off, 64);
    if ((m & 63) == 0) red[m >> 6] = part;
    __syncthreads();
    if (m == 0) {
        float L = (red[0] + red[1] + red[2] + red[3]) * (1.0f / 256.0f);
        Lp[b * 4 + 0] = L;
        Lp[b * 4 + 1] = 1.0f / (256.0f * L);
        Lp[b * 4 + 2] = ALPHA / L;
    }
}

// ---------------------------------------------------------------------------
// K4a: c[b,m] = (dot(Ah[b,m,:], z[b,:]) - y[b,m]) * (1/(M*L_b))
// grid: 2048 blocks x 256 threads
// ---------------------------------------------------------------------------
__global__ __launch_bounds__(256) void k_resid(const __half* __restrict__ Ah,
                                               const float* __restrict__ z,
                                               const float* __restrict__ y,
                                               const float* __restrict__ Lp,
                                               float* __restrict__ c) {
    int bm = blockIdx.x;
    int b = bm >> 8;
    const uint4* arow = (const uint4*)(Ah + (size_t)bm * D);
    const float4* zrow = (const float4*)(z + (size_t)b * D);
    float s = 0.f;
#pragma unroll 4
    for (int i = threadIdx.x; i < D / 8; i += 256) {
        uint4 a = arow[i];
        const __half2* hp = (const __half2*)&a;
        float4 z0 = zrow[2 * i], z1 = zrow[2 * i + 1];
        float2 f0 = __half22float2(hp[0]);
        float2 f1 = __half22float2(hp[1]);
        float2 f2 = __half22float2(hp[2]);
        float2 f3 = __half22float2(hp[3]);
        s += f0.x * z0.x + f0.y * z0.y + f1.x * z0.z + f1.y * z0.w +
             f2.x * z1.x + f2.y * z1.y + f3.x * z1.z + f3.y * z1.w;
    }
    __shared__ float red[4];
    for (int off = 32; off > 0; off >>= 1) s += __shfl_down(s, off, 64);
    if ((threadIdx.x & 63) == 0) red[threadIdx.x >> 6] = s;
    __syncthreads();
    if (threadIdx.x == 0) {
        float sv = red[0] + red[1] + red[2] + red[3];
        c[bm] = (sv - y[bm]) * Lp[b * 4 + 1];
    }
}

// ---------------------------------------------------------------------------
// K4b: w_new = soft(z - Ah^T c, ALPHA/L); z_new = w_new + beta*(w_new - w_old)
// block: batch b, 2048-wide d-tile, thread owns 8 d's (uint4 = 8 halves/row).
// grid: 8 * 32 = 256 blocks x 256 threads (1 block/CU; m-loop unrolled x8 for
// enough loads in flight: 4 waves * 8 * 1KB = 32KB/CU >> 9.2KB needed at 900cy)
// ---------------------------------------------------------------------------
__global__ __launch_bounds__(256) void k_update(const __half* __restrict__ Ah,
                                                const float* __restrict__ cc,
                                                const float* __restrict__ Lp,
                                                float* __restrict__ z,
                                                float* __restrict__ w,
                                                float beta) {
    int blk = blockIdx.x;
    int b = blk >> 5;
    int dt = (blk & 31) << 11;  // 2048 cols per block
    __shared__ float sc[M];
    sc[threadIdx.x] = cc[b * M + threadIdx.x];
    __syncthreads();

    const __half* Ap = Ah + (size_t)b * M * D + dt + (threadIdx.x << 3);
    float acc[8] = {};
#pragma unroll 8
    for (int m = 0; m < M; ++m) {
        uint4 a = *(const uint4*)Ap;
        Ap += D;
        const __half2* hp = (const __half2*)&a;
        float cm = sc[m];
        float2 f0 = __half22float2(hp[0]);
        float2 f1 = __half22float2(hp[1]);
        float2 f2 = __half22float2(hp[2]);
        float2 f3 = __half22float2(hp[3]);
        acc[0] += f0.x * cm; acc[1] += f0.y * cm;
        acc[2] += f1.x * cm; acc[3] += f1.y * cm;
        acc[4] += f2.x * cm; acc[5] += f2.y * cm;
        acc[6] += f3.x * cm; acc[7] += f3.y * cm;
    }
    size_t zi = (size_t)b * D + dt + (threadIdx.x << 3);
    float4 zv0 = *(const float4*)(z + zi);
    float4 zv1 = *(const float4*)(z + zi + 4);
    float4 wv0 = *(const float4*)(w + zi);
    float4 wv1 = *(const float4*)(w + zi + 4);
    float thr = Lp[b * 4 + 2];

    float zvv[8] = {zv0.x, zv0.y, zv0.z, zv0.w, zv1.x, zv1.y, zv1.z, zv1.w};
    float wvv[8] = {wv0.x, wv0.y, wv0.z, wv0.w, wv1.x, wv1.y, wv1.z, wv1.w};
    float wn[8], zn[8];
#pragma unroll
    for (int j = 0; j < 8; ++j) {
        float cand = zvv[j] - acc[j];
        float a1 = fabsf(cand) - thr;
        wn[j] = a1 > 0.f ? copysignf(a1, cand) : 0.f;
        zn[j] = wn[j] + beta * (wn[j] - wvv[j]);
    }
    *(float4*)(w + zi)     = make_float4(wn[0], wn[1], wn[2], wn[3]);
    *(float4*)(w + zi + 4) = make_float4(wn[4], wn[5], wn[6], wn[7]);
    *(float4*)(z + zi)     = make_float4(zn[0], zn[1], zn[2], zn[3]);
    *(float4*)(z + zi + 4) = make_float4(zn[4], zn[5], zn[6], zn[7]);
}

// ---------------------------------------------------------------------------
extern "C" void kernel_launch(void* const* d_in, const int* in_sizes, int n_in,
                              void* d_out, int out_size, void* d_ws, size_t ws_size,
                              hipStream_t stream) {
    (void)in_sizes; (void)n_in; (void)out_size; (void)ws_size;
    const float* x = (const float*)d_in[0];        // [B, D]
    const float* A = (const float*)d_in[1];        // [B, M, D]
    float* w = (float*)d_out;                      // [B, D]

    // workspace layout: Ah (fp16, 256 MiB) first, fp32 scratch after
    __half* Ah = (__half*)d_ws;
    float* ws = (float*)((char*)d_ws + (size_t)B * M * D * sizeof(__half));
    float* y  = ws;                 // 2048
    float* u  = ws + 2048;          // 2048
    float* Lp = ws + 4096;          // 32
    float* c  = ws + 4128;          // 2048
    float* z  = ws + 8192;          // 524288 (16B aligned)
    float* G  = ws + 8192 + 524288; // 524288

    hipMemsetAsync(G, 0, (size_t)B * M * M * sizeof(float), stream);
    hipMemsetAsync(z, 0, (size_t)B * D * sizeof(float), stream);
    hipMemsetAsync(w, 0, (size_t)B * D * sizeof(float), stream);

    k_conv<<<16384, 256, 0, stream>>>(A, Ah);
    k_y_u0<<<B * M, 256, 0, stream>>>(Ah, x, y, u);
    k_gram<<<B * 10 * 16, 256, 0, stream>>>(Ah, G);
    k_power<<<B, 256, 0, stream>>>(G, u, Lp);

    double t = 1.0;
    for (int k = 0; k < N_ITERS; ++k) {
        double tn = 0.5 * (1.0 + sqrt(1.0 + 4.0 * t * t));
        float beta = (float)((t - 1.0) / tn);
        k_resid<<<B * M, 256, 0, stream>>>(Ah, z, y, Lp, c);
        k_update<<<B * 64 / 2, 256, 0, stream>>>(Ah, c, Lp, z, w, beta);
        t = tn;
    }
}